// Round 1
// baseline (2407.970 us; speedup 1.0000x reference)
//
#include <hip/hip_runtime.h>
#include <hip/hip_bf16.h>

typedef unsigned short u16;
typedef unsigned int u32;
typedef unsigned long long u64;
typedef __attribute__((ext_vector_type(8))) short bf16x8;   // 8 bf16 in 4 VGPRs
typedef __attribute__((ext_vector_type(4))) float f32x4;    // MFMA acc
typedef __attribute__((ext_vector_type(4))) unsigned int u32x4;

#define MFMA16(a, b, c) __builtin_amdgcn_mfma_f32_16x16x32_bf16((a), (b), (c), 0, 0, 0)

static constexpr int Ee = 300, EP = 320, Hh = 1024, G3 = 3072;
static constexpr int Bb = 64, Tt = 512;

// workspace layout (bytes)
static constexpr long OFF_GX   = 0L;                      // [512][3072][64] bf16 = 201326592
static constexpr long OFF_EMB  = 201326592L;              // [32768][320] bf16   = 20971520
static constexpr long OFF_WIH  = 222298112L;              // [3072][320] bf16    = 1966080
static constexpr long OFF_WHH  = 224264192L;              // [3072][1024] bf16   = 6291456
static constexpr long OFF_HBUF = 230555648L;              // 4 grp x 2 slot x [16][1024] u32 tagged

__device__ __forceinline__ u16 f2bf(float f) {
    union { float f; unsigned u; } v; v.f = f;
    unsigned u = v.u;
    return (u16)((u + 0x7fffu + ((u >> 16) & 1u)) >> 16);   // RNE
}
__device__ __forceinline__ float bf2f(u16 u) {
    union { unsigned u; float f; } v; v.u = ((unsigned)u) << 16;
    return v.f;
}
__device__ __forceinline__ float fast_sigmoid(float x) {
    return 1.f / (1.f + __expf(-x));
}
__device__ __forceinline__ float fast_tanh(float x) {
    float ax = fabsf(x);
    float e = __expf(-2.f * ax);
    float t = (1.f - e) / (1.f + e);
    return copysignf(t, x);
}

// ---------------------------------------------------------------- prep ------
static constexpr long R0 = (long)Bb * Tt * EP;   // emb gather (bf16, padded)
static constexpr long R1 = (long)G3 * EP;        // W_ih -> bf16 padded
static constexpr long R2 = (long)G3 * Hh;        // W_hh -> bf16
static constexpr long R3 = 131072;               // tagged h words: slot0 = (0|tag0), slot1 = sentinel
static constexpr long R5 = 320;                  // out = bias (d_out is poisoned!)

__global__ void prep_kernel(const int* __restrict__ x, const float* __restrict__ emb,
                            const float* __restrict__ wih, const float* __restrict__ whh,
                            const float* __restrict__ bfc,
                            u16* __restrict__ emb_bf, u16* __restrict__ wih_bf,
                            u16* __restrict__ whh_bf, u32* __restrict__ h32,
                            float* __restrict__ out) {
    const long total = R0 + R1 + R2 + R3 + R5;
    for (long i = (long)blockIdx.x * blockDim.x + threadIdx.x; i < total;
         i += (long)gridDim.x * blockDim.x) {
        if (i < R0) {
            const int m = (int)(i / EP), k = (int)(i % EP);
            const int b = m & 63, t = m >> 6;
            u16 v = 0;
            if (k < Ee) {
                const int xi = x[b * Tt + t];
                v = f2bf(emb[(size_t)xi * Ee + k]);
            }
            emb_bf[i] = v;
        } else if (i < R0 + R1) {
            const long j = i - R0;
            const int k = (int)(j % EP);
            const int n = (int)(j / EP);
            wih_bf[j] = (k < Ee) ? f2bf(wih[(size_t)n * Ee + k]) : (u16)0;
        } else if (i < R0 + R1 + R2) {
            const long j = i - R0 - R1;
            whh_bf[j] = f2bf(whh[j]);
        } else if (i < R0 + R1 + R2 + R3) {
            const long j = i - R0 - R1 - R2;
            // per group: slot0 (16384 words) = payload 0 / tag 0 == h_0; slot1 = tag 0xFFFF
            h32[j] = ((j >> 14) & 1) ? 0xFFFFu : 0u;
        } else {
            const long j = i - R0 - R1 - R2 - R3;
            out[j] = bfc[j % 5];
        }
    }
}

// ------------------------------------------------------------- gx GEMM ------
// gx[t][n][b] = sum_k emb_bf[m=t*64+b][k] * wih_bf[n][k] + b_ih[n], bf16 out.
__global__ __launch_bounds__(256, 2)
void gx_gemm(const u16* __restrict__ A, const u16* __restrict__ Bm,
             const float* __restrict__ bih, u16* __restrict__ gx) {
    __shared__ __align__(16) u16 lA[128 * 32];
    __shared__ __align__(16) u16 lB[128 * 32];
    const int tid = threadIdx.x;
    const int lane = tid & 63;
    const int wv = tid >> 6;
    const int quad = lane >> 4, l15 = lane & 15;
    const int m0 = blockIdx.x * 128;
    const int n0 = blockIdx.y * 128;
    const int mo = (wv & 1) * 64, no = (wv >> 1) * 64;
    const int srow = tid >> 2;
    const int sseg = tid & 3;

    f32x4 acc[4][4] = {};

    for (int s = 0; s < 10; ++s) {
        const int k0 = s * 32;
        __syncthreads();
#pragma unroll
        for (int p = 0; p < 2; ++p) {
            const u16* ga = A + (size_t)(m0 + p * 64 + srow) * EP + k0 + sseg * 8;
            u16* la = &lA[p * 2048 + wv * 512];
            __builtin_amdgcn_global_load_lds(
                (const __attribute__((address_space(1))) void*)ga,
                (__attribute__((address_space(3))) void*)la, 16, 0, 0);
            const u16* gb = Bm + (size_t)(n0 + p * 64 + srow) * EP + k0 + sseg * 8;
            u16* lb = &lB[p * 2048 + wv * 512];
            __builtin_amdgcn_global_load_lds(
                (const __attribute__((address_space(1))) void*)gb,
                (__attribute__((address_space(3))) void*)lb, 16, 0, 0);
        }
        __syncthreads();

        bf16x8 af[4], bfr[4];
#pragma unroll
        for (int mt = 0; mt < 4; ++mt)
            af[mt] = *(const bf16x8*)&lA[(mo + mt * 16 + l15) * 32 + quad * 8];
#pragma unroll
        for (int nt = 0; nt < 4; ++nt)
            bfr[nt] = *(const bf16x8*)&lB[(no + nt * 16 + l15) * 32 + quad * 8];
#pragma unroll
        for (int mt = 0; mt < 4; ++mt)
#pragma unroll
            for (int nt = 0; nt < 4; ++nt)
                acc[mt][nt] = MFMA16(af[mt], bfr[nt], acc[mt][nt]);
    }

    // C layout: row m = quad*4+r, col n = lane&15
#pragma unroll
    for (int mt = 0; mt < 4; ++mt) {
        const int mg = m0 + mo + mt * 16 + quad * 4;
        const int t = mg >> 6, b0 = mg & 63;
#pragma unroll
        for (int nt = 0; nt < 4; ++nt) {
            const int n = n0 + no + nt * 16 + l15;
            const float bi = bih[n];
            ushort4 vv;
            vv.x = f2bf(acc[mt][nt][0] + bi);
            vv.y = f2bf(acc[mt][nt][1] + bi);
            vv.z = f2bf(acc[mt][nt][2] + bi);
            vv.w = f2bf(acc[mt][nt][3] + bi);
            *(ushort4*)&gx[((size_t)t * G3 + n) * 64 + b0] = vv;
        }
    }
}

// ---------------------------------------------------------------- scan ------
// 128 blocks x 512 thr = 4 batch groups x 32 col blocks. Flag-free sync:
// every h element travels as u32 = (bf16 << 16) | step_tag. Dword stores are
// atomic, so each word self-validates — producers fire tagged stores with NO
// drain and NO flag; consumers do a single retry-load (8x dwordx4 sc0 sc1,
// one vmcnt) and check every word's tag == t. Slot-reuse safety (2 slots):
// producing h_{t+2} requires having consumed h_{t+1} (block-wide barriers),
// which proves all readers of slot t&1 finished step t — so exact-tag spin
// cannot be overrun / cannot deadlock.
__global__ __launch_bounds__(512, 2)
void scan_kernel(const u16* __restrict__ whh, const float* __restrict__ bhh,
                 const u16* __restrict__ gx, u32* __restrict__ hball,
                 const float* __restrict__ wfc, float* __restrict__ out) {
    __shared__ __align__(16) u16 lh[16 * 1032];           // staged h (row 258 u64)
    __shared__ __align__(16) float red[2][3][4][16 * 20]; // [nh][g][kq][m*20+n]

    const int bid = blockIdx.x;
    const int bg = bid >> 5;          // batch group 0..3 (rows 16bg..+16)
    const int cg = bid & 31;          // col group 0..31 (cols 32cg..+32)
    const int tid = threadIdx.x;
    const int w = tid >> 6;           // wave 0..7
    const int lane = tid & 63;
    const int kq = w & 3;             // K-quarter
    const int nh = w >> 2;            // col-half
    const int quad = lane >> 4, l15 = lane & 15;
    const int c0 = cg * 32;
    const bool isGate = (w == 3) || (w == 4);
    const int gnh = (w == 3) ? 0 : 1;

    // register-resident W: B-frag for col c0+nh*16+l15, gate g, k-chunk kq*8+s
    bf16x8 wf[3][8];
#pragma unroll
    for (int g = 0; g < 3; ++g) {
        const size_t rbase = (size_t)(g * 1024 + c0 + nh * 16 + l15) * 1024;
#pragma unroll
        for (int s = 0; s < 8; ++s)
            wf[g][s] = *(const bf16x8*)&whh[rbase + (kq * 8 + s) * 32 + quad * 8];
    }

    // gate-wave per-lane state: (b = bg*16+l15, j = c0+gnh*16+quad*4+jj)
    float bh[3][4];
    u16 gxv[3][4];
    float hO[4] = {0.f, 0.f, 0.f, 0.f};
    if (isGate) {
#pragma unroll
        for (int g = 0; g < 3; ++g)
#pragma unroll
            for (int jj = 0; jj < 4; ++jj) {
                const int jglob = c0 + gnh * 16 + quad * 4 + jj;
                bh[g][jj] = bhh[g * 1024 + jglob];
                gxv[g][jj] = gx[((size_t)g * 1024 + jglob) * 64 + bg * 16 + l15];
            }
    }

    u32* hb = hball + (size_t)bg * 32768;   // group base (2 slots x 16384 u32)
    u64* lhq = (u64*)lh;
    const int t4 = tid << 2;                // word offset of this thread's dwordx4
    const int srow0 = tid >> 8;             // 0/1 row parity within round
    const int sc4 = tid & 255;              // u64 column within LDS row

    for (int t = 0; t < 512; ++t) {
        const u32* hs = hb + ((t & 1) << 14);
        const u32 tg = (u32)t;

        // ---- fused poll+pull: retry tagged loads until all 32 tags == t ----
        const u32* p0 = hs + t4;
        const u32* p1 = hs + 2048 + t4;
        const u32* p2 = hs + 4096 + t4;
        const u32* p3 = hs + 6144 + t4;
        const u32* p4 = hs + 8192 + t4;
        const u32* p5 = hs + 10240 + t4;
        const u32* p6 = hs + 12288 + t4;
        const u32* p7 = hs + 14336 + t4;
        u32x4 q0, q1, q2, q3, q4, q5, q6, q7;
        for (;;) {
            asm volatile(
                "global_load_dwordx4 %0, %8, off sc0 sc1\n\t"
                "global_load_dwordx4 %1, %9, off sc0 sc1\n\t"
                "global_load_dwordx4 %2, %10, off sc0 sc1\n\t"
                "global_load_dwordx4 %3, %11, off sc0 sc1\n\t"
                "global_load_dwordx4 %4, %12, off sc0 sc1\n\t"
                "global_load_dwordx4 %5, %13, off sc0 sc1\n\t"
                "global_load_dwordx4 %6, %14, off sc0 sc1\n\t"
                "global_load_dwordx4 %7, %15, off sc0 sc1\n\t"
                "s_waitcnt vmcnt(0)"
                : "=&v"(q0), "=&v"(q1), "=&v"(q2), "=&v"(q3),
                  "=&v"(q4), "=&v"(q5), "=&v"(q6), "=&v"(q7)
                : "v"(p0), "v"(p1), "v"(p2), "v"(p3),
                  "v"(p4), "v"(p5), "v"(p6), "v"(p7)
                : "memory");
            bool ok = true;
            ok &= ((q0.x & 0xffffu) == tg); ok &= ((q0.y & 0xffffu) == tg);
            ok &= ((q0.z & 0xffffu) == tg); ok &= ((q0.w & 0xffffu) == tg);
            ok &= ((q1.x & 0xffffu) == tg); ok &= ((q1.y & 0xffffu) == tg);
            ok &= ((q1.z & 0xffffu) == tg); ok &= ((q1.w & 0xffffu) == tg);
            ok &= ((q2.x & 0xffffu) == tg); ok &= ((q2.y & 0xffffu) == tg);
            ok &= ((q2.z & 0xffffu) == tg); ok &= ((q2.w & 0xffffu) == tg);
            ok &= ((q3.x & 0xffffu) == tg); ok &= ((q3.y & 0xffffu) == tg);
            ok &= ((q3.z & 0xffffu) == tg); ok &= ((q3.w & 0xffffu) == tg);
            ok &= ((q4.x & 0xffffu) == tg); ok &= ((q4.y & 0xffffu) == tg);
            ok &= ((q4.z & 0xffffu) == tg); ok &= ((q4.w & 0xffffu) == tg);
            ok &= ((q5.x & 0xffffu) == tg); ok &= ((q5.y & 0xffffu) == tg);
            ok &= ((q5.z & 0xffffu) == tg); ok &= ((q5.w & 0xffffu) == tg);
            ok &= ((q6.x & 0xffffu) == tg); ok &= ((q6.y & 0xffffu) == tg);
            ok &= ((q6.z & 0xffffu) == tg); ok &= ((q6.w & 0xffffu) == tg);
            ok &= ((q7.x & 0xffffu) == tg); ok &= ((q7.y & 0xffffu) == tg);
            ok &= ((q7.z & 0xffffu) == tg); ok &= ((q7.w & 0xffffu) == tg);
            if (__all(ok)) break;
            __builtin_amdgcn_s_sleep(1);
        }

        // ---- strip tags, pack bf16 pairs -> LDS ----
#define UNPK(rr, qq)                                                          \
        {                                                                     \
            const int row = (rr) * 2 + srow0;                                 \
            const u32 lo = (qq.x >> 16) | (qq.y & 0xffff0000u);               \
            const u32 hi = (qq.z >> 16) | (qq.w & 0xffff0000u);               \
            lhq[row * 258 + sc4] = (u64)lo | ((u64)hi << 32);                 \
        }
        UNPK(0, q0) UNPK(1, q1) UNPK(2, q2) UNPK(3, q3)
        UNPK(4, q4) UNPK(5, q5) UNPK(6, q6) UNPK(7, q7)
#undef UNPK
        __syncthreads();                      // sync1: lh ready

        // MFMA over this wave's K-quarter, 3 gates
        bf16x8 af[8];
#pragma unroll
        for (int s = 0; s < 8; ++s)
            af[s] = *(const bf16x8*)&lh[l15 * 1032 + kq * 256 + s * 32 + quad * 8];
        f32x4 acc[3] = {};
#pragma unroll
        for (int s = 0; s < 8; ++s) {
            acc[0] = MFMA16(af[s], wf[0][s], acc[0]);
            acc[1] = MFMA16(af[s], wf[1][s], acc[1]);
            acc[2] = MFMA16(af[s], wf[2][s], acc[2]);
        }
        // transposed red store [m*20+n]: max 2-way conflict (free)
#pragma unroll
        for (int g = 0; g < 3; ++g)
#pragma unroll
            for (int r = 0; r < 4; ++r)
                red[nh][g][kq][(quad * 4 + r) * 20 + l15] = acc[g][r];
        __syncthreads();                      // sync2: red ready

        if (isGate) {
            f32x4 rr[3][4];
#pragma unroll
            for (int g = 0; g < 3; ++g)
#pragma unroll
                for (int k = 0; k < 4; ++k)
                    rr[g][k] = *(const f32x4*)&red[gnh][g][k][l15 * 20 + quad * 4];
            u32 wtag[4];
#pragma unroll
            for (int jj = 0; jj < 4; ++jj) {
                const float s0 = rr[0][0][jj] + rr[0][1][jj] + rr[0][2][jj] + rr[0][3][jj];
                const float s1 = rr[1][0][jj] + rr[1][1][jj] + rr[1][2][jj] + rr[1][3][jj];
                const float s2 = rr[2][0][jj] + rr[2][1][jj] + rr[2][2][jj] + rr[2][3][jj];
                const float rg = fast_sigmoid(bf2f(gxv[0][jj]) + s0 + bh[0][jj]);
                const float zg = fast_sigmoid(bf2f(gxv[1][jj]) + s1 + bh[1][jj]);
                const float ng = fast_tanh(bf2f(gxv[2][jj]) + rg * (s2 + bh[2][jj]));
                const float hv = (1.f - zg) * ng + zg * hO[jj];
                hO[jj] = hv;
                wtag[jj] = ((u32)f2bf(hv) << 16) | (u32)(t + 1);
            }
            if (t < 511) {
                // tagged self-validating stores: no drain, no flag
                u32* hn = hb + (((t + 1) & 1) << 14);
                const int widx = (l15 << 10) + c0 + gnh * 16 + (quad << 2);
                __hip_atomic_store((u64*)&hn[widx],
                                   (u64)wtag[0] | ((u64)wtag[1] << 32),
                                   __ATOMIC_RELAXED, __HIP_MEMORY_SCOPE_AGENT);
                __hip_atomic_store((u64*)&hn[widx + 2],
                                   (u64)wtag[2] | ((u64)wtag[3] << 32),
                                   __ATOMIC_RELAXED, __HIP_MEMORY_SCOPE_AGENT);
                // prefetch next step's gx (read-only, off critical path)
#pragma unroll
                for (int g = 0; g < 3; ++g)
#pragma unroll
                    for (int jj = 0; jj < 4; ++jj)
                        gxv[g][jj] = gx[((size_t)(t + 1) * G3 + g * 1024 + c0 +
                                         gnh * 16 + quad * 4 + jj) * 64 + bg * 16 + l15];
            }
        }
    }

    // FC head from gate-wave registers: hO[jj] = h_T(b=bg*16+l15, j)
    if (isGate) {
#pragma unroll
        for (int p = 0; p < 5; ++p) {
            float v = 0.f;
#pragma unroll
            for (int jj = 0; jj < 4; ++jj)
                v += hO[jj] * wfc[p * 1024 + c0 + gnh * 16 + quad * 4 + jj];
            v += __shfl_xor(v, 16);
            v += __shfl_xor(v, 32);
            if (quad == 0)
                atomicAdd(&out[(bg * 16 + l15) * 5 + p], v);
        }
    }
}

// --------------------------------------------------------------- launch -----
extern "C" void kernel_launch(void* const* d_in, const int* in_sizes, int n_in,
                              void* d_out, int out_size, void* d_ws, size_t ws_size,
                              hipStream_t stream) {
    const int*   x   = (const int*)d_in[0];
    const float* emb = (const float*)d_in[1];
    const float* wih = (const float*)d_in[2];
    const float* whh = (const float*)d_in[3];
    const float* bih = (const float*)d_in[4];
    const float* bhh = (const float*)d_in[5];
    const float* wfc = (const float*)d_in[6];
    const float* bfc = (const float*)d_in[7];
    float* out = (float*)d_out;

    char* ws = (char*)d_ws;
    u16*   gxw   = (u16*)(ws + OFF_GX);
    u16*   embbf = (u16*)(ws + OFF_EMB);
    u16*   wihbf = (u16*)(ws + OFF_WIH);
    u16*   whhbf = (u16*)(ws + OFF_WHH);
    u32*   h32   = (u32*)(ws + OFF_HBUF);

    prep_kernel<<<8192, 256, 0, stream>>>(x, emb, wih, whh, bfc, embbf, wihbf,
                                          whhbf, h32, out);

    gx_gemm<<<dim3(256, 24), 256, 0, stream>>>(embbf, wihbf, bih, gxw);

    scan_kernel<<<128, 512, 0, stream>>>(whhbf, bhh, gxw, h32, wfc, out);
}

// Round 2
// 2301.646 us; speedup vs baseline: 1.0462x; 1.0462x over previous
//
#include <hip/hip_runtime.h>
#include <hip/hip_bf16.h>

typedef unsigned short u16;
typedef unsigned int u32;
typedef unsigned long long u64;
typedef __attribute__((ext_vector_type(8))) short bf16x8;   // 8 bf16 in 4 VGPRs
typedef __attribute__((ext_vector_type(4))) float f32x4;    // MFMA acc
typedef __attribute__((ext_vector_type(4))) unsigned int u32x4;

#define MFMA16(a, b, c) __builtin_amdgcn_mfma_f32_16x16x32_bf16((a), (b), (c), 0, 0, 0)

static constexpr int Ee = 300, EP = 320, Hh = 1024, G3 = 3072;
static constexpr int Bb = 64, Tt = 512;

// workspace layout (bytes)
static constexpr long OFF_GX   = 0L;                      // [512][3072][64] bf16 = 201326592
static constexpr long OFF_EMB  = 201326592L;              // [32768][320] bf16   = 20971520
static constexpr long OFF_WIH  = 222298112L;              // [3072][320] bf16    = 1966080
static constexpr long OFF_WHH  = 224264192L;              // [3072][1024] bf16   = 6291456
static constexpr long OFF_HBUF = 230555648L;              // 4 grp x 2 slot x [16][1024] u32 tagged

__device__ __forceinline__ u16 f2bf(float f) {
    union { float f; unsigned u; } v; v.f = f;
    unsigned u = v.u;
    return (u16)((u + 0x7fffu + ((u >> 16) & 1u)) >> 16);   // RNE
}
__device__ __forceinline__ float bf2f(u16 u) {
    union { unsigned u; float f; } v; v.u = ((unsigned)u) << 16;
    return v.f;
}
__device__ __forceinline__ float fast_sigmoid(float x) {
    return 1.f / (1.f + __expf(-x));
}
__device__ __forceinline__ float fast_tanh(float x) {
    float ax = fabsf(x);
    float e = __expf(-2.f * ax);
    float t = (1.f - e) / (1.f + e);
    return copysignf(t, x);
}

// ---------------------------------------------------------------- prep ------
static constexpr long R0 = (long)Bb * Tt * EP;   // emb gather (bf16, padded)
static constexpr long R1 = (long)G3 * EP;        // W_ih -> bf16 padded
static constexpr long R2 = (long)G3 * Hh;        // W_hh -> bf16
static constexpr long R3 = 131072;               // tagged h words: slot0 = (0|tag0), slot1 = sentinel
static constexpr long R5 = 320;                  // out = bias (d_out is poisoned!)

__global__ void prep_kernel(const int* __restrict__ x, const float* __restrict__ emb,
                            const float* __restrict__ wih, const float* __restrict__ whh,
                            const float* __restrict__ bfc,
                            u16* __restrict__ emb_bf, u16* __restrict__ wih_bf,
                            u16* __restrict__ whh_bf, u32* __restrict__ h32,
                            float* __restrict__ out) {
    const long total = R0 + R1 + R2 + R3 + R5;
    for (long i = (long)blockIdx.x * blockDim.x + threadIdx.x; i < total;
         i += (long)gridDim.x * blockDim.x) {
        if (i < R0) {
            const int m = (int)(i / EP), k = (int)(i % EP);
            const int b = m & 63, t = m >> 6;
            u16 v = 0;
            if (k < Ee) {
                const int xi = x[b * Tt + t];
                v = f2bf(emb[(size_t)xi * Ee + k]);
            }
            emb_bf[i] = v;
        } else if (i < R0 + R1) {
            const long j = i - R0;
            const int k = (int)(j % EP);
            const int n = (int)(j / EP);
            wih_bf[j] = (k < Ee) ? f2bf(wih[(size_t)n * Ee + k]) : (u16)0;
        } else if (i < R0 + R1 + R2) {
            const long j = i - R0 - R1;
            whh_bf[j] = f2bf(whh[j]);
        } else if (i < R0 + R1 + R2 + R3) {
            const long j = i - R0 - R1 - R2;
            // per group: slot0 (16384 words) = payload 0 / tag 0 == h_0; slot1 = tag 0xFFFF
            h32[j] = ((j >> 14) & 1) ? 0xFFFFu : 0u;
        } else {
            const long j = i - R0 - R1 - R2 - R3;
            out[j] = bfc[j % 5];
        }
    }
}

// ------------------------------------------------------------- gx GEMM ------
// gx[t][n][b] = sum_k emb_bf[m=t*64+b][k] * wih_bf[n][k] + b_ih[n], bf16 out.
__global__ __launch_bounds__(256, 2)
void gx_gemm(const u16* __restrict__ A, const u16* __restrict__ Bm,
             const float* __restrict__ bih, u16* __restrict__ gx) {
    __shared__ __align__(16) u16 lA[128 * 32];
    __shared__ __align__(16) u16 lB[128 * 32];
    const int tid = threadIdx.x;
    const int lane = tid & 63;
    const int wv = tid >> 6;
    const int quad = lane >> 4, l15 = lane & 15;
    const int m0 = blockIdx.x * 128;
    const int n0 = blockIdx.y * 128;
    const int mo = (wv & 1) * 64, no = (wv >> 1) * 64;
    const int srow = tid >> 2;
    const int sseg = tid & 3;

    f32x4 acc[4][4] = {};

    for (int s = 0; s < 10; ++s) {
        const int k0 = s * 32;
        __syncthreads();
#pragma unroll
        for (int p = 0; p < 2; ++p) {
            const u16* ga = A + (size_t)(m0 + p * 64 + srow) * EP + k0 + sseg * 8;
            u16* la = &lA[p * 2048 + wv * 512];
            __builtin_amdgcn_global_load_lds(
                (const __attribute__((address_space(1))) void*)ga,
                (__attribute__((address_space(3))) void*)la, 16, 0, 0);
            const u16* gb = Bm + (size_t)(n0 + p * 64 + srow) * EP + k0 + sseg * 8;
            u16* lb = &lB[p * 2048 + wv * 512];
            __builtin_amdgcn_global_load_lds(
                (const __attribute__((address_space(1))) void*)gb,
                (__attribute__((address_space(3))) void*)lb, 16, 0, 0);
        }
        __syncthreads();

        bf16x8 af[4], bfr[4];
#pragma unroll
        for (int mt = 0; mt < 4; ++mt)
            af[mt] = *(const bf16x8*)&lA[(mo + mt * 16 + l15) * 32 + quad * 8];
#pragma unroll
        for (int nt = 0; nt < 4; ++nt)
            bfr[nt] = *(const bf16x8*)&lB[(no + nt * 16 + l15) * 32 + quad * 8];
#pragma unroll
        for (int mt = 0; mt < 4; ++mt)
#pragma unroll
            for (int nt = 0; nt < 4; ++nt)
                acc[mt][nt] = MFMA16(af[mt], bfr[nt], acc[mt][nt]);
    }

    // C layout: row m = quad*4+r, col n = lane&15
#pragma unroll
    for (int mt = 0; mt < 4; ++mt) {
        const int mg = m0 + mo + mt * 16 + quad * 4;
        const int t = mg >> 6, b0 = mg & 63;
#pragma unroll
        for (int nt = 0; nt < 4; ++nt) {
            const int n = n0 + no + nt * 16 + l15;
            const float bi = bih[n];
            ushort4 vv;
            vv.x = f2bf(acc[mt][nt][0] + bi);
            vv.y = f2bf(acc[mt][nt][1] + bi);
            vv.z = f2bf(acc[mt][nt][2] + bi);
            vv.w = f2bf(acc[mt][nt][3] + bi);
            *(ushort4*)&gx[((size_t)t * G3 + n) * 64 + b0] = vv;
        }
    }
}

// ---------------------------------------------------------------- scan ------
// 128 blocks x 512 thr = 4 batch groups x 32 col blocks. Flag-free sync:
// every h element travels as u32 = (bf16 << 16) | step_tag. Dword stores are
// atomic, so each word self-validates — producers fire tagged stores with NO
// drain and NO flag; consumers retry-load until tags == t. Retry is PARTIAL:
// a per-wave pending mask over the 8 dwordx4 chunks; only chunks whose tags
// haven't matched are reloaded (wave-uniform branches via __all), so steady
// traffic is one pull + laggard chunks, not full-buffer re-pulls (the round-1
// regression). Slot-reuse safety (2 slots): producing h_{t+2} requires having
// consumed h_{t+1} (block-wide barriers), which proves all readers of slot
// t&1 finished step t — exact-tag spin cannot be overrun / cannot deadlock.
__global__ __launch_bounds__(512, 2)
void scan_kernel(const u16* __restrict__ whh, const float* __restrict__ bhh,
                 const u16* __restrict__ gx, u32* __restrict__ hball,
                 const float* __restrict__ wfc, float* __restrict__ out) {
    __shared__ __align__(16) u16 lh[16 * 1032];           // staged h (row 258 u64)
    __shared__ __align__(16) float red[2][3][4][16 * 20]; // [nh][g][kq][m*20+n]

    const int bid = blockIdx.x;
    const int bg = bid >> 5;          // batch group 0..3 (rows 16bg..+16)
    const int cg = bid & 31;          // col group 0..31 (cols 32cg..+32)
    const int tid = threadIdx.x;
    const int w = tid >> 6;           // wave 0..7
    const int lane = tid & 63;
    const int kq = w & 3;             // K-quarter
    const int nh = w >> 2;            // col-half
    const int quad = lane >> 4, l15 = lane & 15;
    const int c0 = cg * 32;
    const bool isGate = (w == 3) || (w == 4);
    const int gnh = (w == 3) ? 0 : 1;

    // register-resident W: B-frag for col c0+nh*16+l15, gate g, k-chunk kq*8+s
    bf16x8 wf[3][8];
#pragma unroll
    for (int g = 0; g < 3; ++g) {
        const size_t rbase = (size_t)(g * 1024 + c0 + nh * 16 + l15) * 1024;
#pragma unroll
        for (int s = 0; s < 8; ++s)
            wf[g][s] = *(const bf16x8*)&whh[rbase + (kq * 8 + s) * 32 + quad * 8];
    }

    // gate-wave per-lane state: (b = bg*16+l15, j = c0+gnh*16+quad*4+jj)
    float bh[3][4];
    u16 gxv[3][4];
    float hO[4] = {0.f, 0.f, 0.f, 0.f};
    if (isGate) {
#pragma unroll
        for (int g = 0; g < 3; ++g)
#pragma unroll
            for (int jj = 0; jj < 4; ++jj) {
                const int jglob = c0 + gnh * 16 + quad * 4 + jj;
                bh[g][jj] = bhh[g * 1024 + jglob];
                gxv[g][jj] = gx[((size_t)g * 1024 + jglob) * 64 + bg * 16 + l15];
            }
    }

    u32* hb = hball + (size_t)bg * 32768;   // group base (2 slots x 16384 u32)
    u64* lhq = (u64*)lh;
    const int t4 = tid << 2;                // word offset of this thread's dwordx4
    const int srow0 = tid >> 8;             // 0/1 row parity within round
    const int sc4 = tid & 255;              // u64 column within LDS row

    for (int t = 0; t < 512; ++t) {
        const u32* hs = hb + ((t & 1) << 14);
        const u32 tg = (u32)t;

        // ---- partial-retry tagged pull: reload only stale chunks ----
        const u32* p0 = hs + t4;
        const u32* p1 = hs + 2048 + t4;
        const u32* p2 = hs + 4096 + t4;
        const u32* p3 = hs + 6144 + t4;
        const u32* p4 = hs + 8192 + t4;
        const u32* p5 = hs + 10240 + t4;
        const u32* p6 = hs + 12288 + t4;
        const u32* p7 = hs + 14336 + t4;
        u32x4 q0, q1, q2, q3, q4, q5, q6, q7;
        {
            u32 pend = 0xffu;
            do {
                if (pend & 0x01u) asm volatile("global_load_dwordx4 %0, %1, off sc0 sc1" : "=&v"(q0) : "v"(p0) : "memory");
                if (pend & 0x02u) asm volatile("global_load_dwordx4 %0, %1, off sc0 sc1" : "=&v"(q1) : "v"(p1) : "memory");
                if (pend & 0x04u) asm volatile("global_load_dwordx4 %0, %1, off sc0 sc1" : "=&v"(q2) : "v"(p2) : "memory");
                if (pend & 0x08u) asm volatile("global_load_dwordx4 %0, %1, off sc0 sc1" : "=&v"(q3) : "v"(p3) : "memory");
                if (pend & 0x10u) asm volatile("global_load_dwordx4 %0, %1, off sc0 sc1" : "=&v"(q4) : "v"(p4) : "memory");
                if (pend & 0x20u) asm volatile("global_load_dwordx4 %0, %1, off sc0 sc1" : "=&v"(q5) : "v"(p5) : "memory");
                if (pend & 0x40u) asm volatile("global_load_dwordx4 %0, %1, off sc0 sc1" : "=&v"(q6) : "v"(p6) : "memory");
                if (pend & 0x80u) asm volatile("global_load_dwordx4 %0, %1, off sc0 sc1" : "=&v"(q7) : "v"(p7) : "memory");
                asm volatile("s_waitcnt vmcnt(0)" ::: "memory");
                __builtin_amdgcn_sched_barrier(0);
                const u32 before = pend;
#define CHK(bit, qq)                                                          \
                if (pend & (bit)) {                                           \
                    const u32 d = ((qq.x ^ tg) | (qq.y ^ tg) |                \
                                   (qq.z ^ tg) | (qq.w ^ tg)) & 0xffffu;      \
                    if (__all(d == 0)) pend &= ~(u32)(bit);                   \
                }
                CHK(0x01u, q0) CHK(0x02u, q1) CHK(0x04u, q2) CHK(0x08u, q3)
                CHK(0x10u, q4) CHK(0x20u, q5) CHK(0x40u, q6) CHK(0x80u, q7)
#undef CHK
                if (pend && pend == before) __builtin_amdgcn_s_sleep(1);
            } while (pend);
        }

        // ---- strip tags, pack bf16 pairs -> LDS ----
#define UNPK(rr, qq)                                                          \
        {                                                                     \
            const int row = (rr) * 2 + srow0;                                 \
            const u32 lo = (qq.x >> 16) | (qq.y & 0xffff0000u);               \
            const u32 hi = (qq.z >> 16) | (qq.w & 0xffff0000u);               \
            lhq[row * 258 + sc4] = (u64)lo | ((u64)hi << 32);                 \
        }
        UNPK(0, q0) UNPK(1, q1) UNPK(2, q2) UNPK(3, q3)
        UNPK(4, q4) UNPK(5, q5) UNPK(6, q6) UNPK(7, q7)
#undef UNPK
        __syncthreads();                      // sync1: lh ready

        // MFMA over this wave's K-quarter, 3 gates
        bf16x8 af[8];
#pragma unroll
        for (int s = 0; s < 8; ++s)
            af[s] = *(const bf16x8*)&lh[l15 * 1032 + kq * 256 + s * 32 + quad * 8];
        f32x4 acc[3] = {};
#pragma unroll
        for (int s = 0; s < 8; ++s) {
            acc[0] = MFMA16(af[s], wf[0][s], acc[0]);
            acc[1] = MFMA16(af[s], wf[1][s], acc[1]);
            acc[2] = MFMA16(af[s], wf[2][s], acc[2]);
        }
        // transposed red store [m*20+n]: max 2-way conflict (free)
#pragma unroll
        for (int g = 0; g < 3; ++g)
#pragma unroll
            for (int r = 0; r < 4; ++r)
                red[nh][g][kq][(quad * 4 + r) * 20 + l15] = acc[g][r];
        __syncthreads();                      // sync2: red ready

        if (isGate) {
            f32x4 rr[3][4];
#pragma unroll
            for (int g = 0; g < 3; ++g)
#pragma unroll
                for (int k = 0; k < 4; ++k)
                    rr[g][k] = *(const f32x4*)&red[gnh][g][k][l15 * 20 + quad * 4];
            u32 wtag[4];
#pragma unroll
            for (int jj = 0; jj < 4; ++jj) {
                const float s0 = rr[0][0][jj] + rr[0][1][jj] + rr[0][2][jj] + rr[0][3][jj];
                const float s1 = rr[1][0][jj] + rr[1][1][jj] + rr[1][2][jj] + rr[1][3][jj];
                const float s2 = rr[2][0][jj] + rr[2][1][jj] + rr[2][2][jj] + rr[2][3][jj];
                const float rg = fast_sigmoid(bf2f(gxv[0][jj]) + s0 + bh[0][jj]);
                const float zg = fast_sigmoid(bf2f(gxv[1][jj]) + s1 + bh[1][jj]);
                const float ng = fast_tanh(bf2f(gxv[2][jj]) + rg * (s2 + bh[2][jj]));
                const float hv = (1.f - zg) * ng + zg * hO[jj];
                hO[jj] = hv;
                wtag[jj] = ((u32)f2bf(hv) << 16) | (u32)(t + 1);
            }
            if (t < 511) {
                // tagged self-validating stores: no drain, no flag
                u32* hn = hb + (((t + 1) & 1) << 14);
                const int widx = (l15 << 10) + c0 + gnh * 16 + (quad << 2);
                __hip_atomic_store((u64*)&hn[widx],
                                   (u64)wtag[0] | ((u64)wtag[1] << 32),
                                   __ATOMIC_RELAXED, __HIP_MEMORY_SCOPE_AGENT);
                __hip_atomic_store((u64*)&hn[widx + 2],
                                   (u64)wtag[2] | ((u64)wtag[3] << 32),
                                   __ATOMIC_RELAXED, __HIP_MEMORY_SCOPE_AGENT);
                // prefetch next step's gx (read-only, off critical path)
#pragma unroll
                for (int g = 0; g < 3; ++g)
#pragma unroll
                    for (int jj = 0; jj < 4; ++jj)
                        gxv[g][jj] = gx[((size_t)(t + 1) * G3 + g * 1024 + c0 +
                                         gnh * 16 + quad * 4 + jj) * 64 + bg * 16 + l15];
            }
        }
    }

    // FC head from gate-wave registers: hO[jj] = h_T(b=bg*16+l15, j)
    if (isGate) {
#pragma unroll
        for (int p = 0; p < 5; ++p) {
            float v = 0.f;
#pragma unroll
            for (int jj = 0; jj < 4; ++jj)
                v += hO[jj] * wfc[p * 1024 + c0 + gnh * 16 + quad * 4 + jj];
            v += __shfl_xor(v, 16);
            v += __shfl_xor(v, 32);
            if (quad == 0)
                atomicAdd(&out[(bg * 16 + l15) * 5 + p], v);
        }
    }
}

// --------------------------------------------------------------- launch -----
extern "C" void kernel_launch(void* const* d_in, const int* in_sizes, int n_in,
                              void* d_out, int out_size, void* d_ws, size_t ws_size,
                              hipStream_t stream) {
    const int*   x   = (const int*)d_in[0];
    const float* emb = (const float*)d_in[1];
    const float* wih = (const float*)d_in[2];
    const float* whh = (const float*)d_in[3];
    const float* bih = (const float*)d_in[4];
    const float* bhh = (const float*)d_in[5];
    const float* wfc = (const float*)d_in[6];
    const float* bfc = (const float*)d_in[7];
    float* out = (float*)d_out;

    char* ws = (char*)d_ws;
    u16*   gxw   = (u16*)(ws + OFF_GX);
    u16*   embbf = (u16*)(ws + OFF_EMB);
    u16*   wihbf = (u16*)(ws + OFF_WIH);
    u16*   whhbf = (u16*)(ws + OFF_WHH);
    u32*   h32   = (u32*)(ws + OFF_HBUF);

    prep_kernel<<<8192, 256, 0, stream>>>(x, emb, wih, whh, bfc, embbf, wihbf,
                                          whhbf, h32, out);

    gx_gemm<<<dim3(256, 24), 256, 0, stream>>>(embbf, wihbf, bih, gxw);

    scan_kernel<<<128, 512, 0, stream>>>(whhbf, bhh, gxw, h32, wfc, out);
}